// Round 6
// baseline (315.165 us; speedup 1.0000x reference)
//
#include <hip/hip_runtime.h>
#include <hip/hip_bf16.h>
#include <stdint.h>

#define S_LEN 2048
#define D_MOD 1024
#define NHEAD 16
#define BATCH 2
#define M_TOT (BATCH * S_LEN)  // 4096

typedef __bf16 bf16_t;
typedef __bf16 bf16x8 __attribute__((ext_vector_type(8)));
typedef __bf16 bf16x4 __attribute__((ext_vector_type(4)));
typedef float f32x4 __attribute__((ext_vector_type(4)));

typedef __attribute__((address_space(1))) void gas_void;
typedef __attribute__((address_space(3))) void las_void;

__device__ __forceinline__ void gload_lds16(const void* g, void* l) {
#if defined(__has_builtin) && __has_builtin(__builtin_amdgcn_global_load_lds)
  __builtin_amdgcn_global_load_lds((gas_void*)g, (las_void*)l, 16u, 0, 0u);
#else
  *(bf16x8*)l = *(const bf16x8*)g;
#endif
}

__device__ __forceinline__ f32x4 mfma16(bf16x8 a, bf16x8 b, f32x4 c) {
  return __builtin_amdgcn_mfma_f32_16x16x32_bf16(a, b, c, 0, 0, 0);
}

// ---------------- fp32 -> bf16 convert (queries/keys/values), float4 per thread ----------------
__global__ __launch_bounds__(256) void cvt3_kernel(
    const float* __restrict__ a, const float* __restrict__ b, const float* __restrict__ c,
    bf16_t* __restrict__ oa, bf16_t* __restrict__ ob, bf16_t* __restrict__ oc)
{
  const float* in  = blockIdx.z == 0 ? a : (blockIdx.z == 1 ? b : c);
  bf16_t*      out = blockIdx.z == 0 ? oa : (blockIdx.z == 1 ? ob : oc);
  int i = blockIdx.x * 256 + threadIdx.x;
  float4 v = ((const float4*)in)[i];
  bf16x4 o;
  o[0] = (bf16_t)v.x; o[1] = (bf16_t)v.y; o[2] = (bf16_t)v.z; o[3] = (bf16_t)v.w;
  ((bf16x4*)out)[i] = o;
}

// ---------------- weight transpose + convert: W[K][N] f32 -> Wt[N][K] bf16 ----------------
__global__ __launch_bounds__(256) void wtrans_kernel(
    const float* __restrict__ w0, const float* __restrict__ w1,
    const float* __restrict__ w2, const float* __restrict__ w3,
    bf16_t* __restrict__ t0, bf16_t* __restrict__ t1,
    bf16_t* __restrict__ t2, bf16_t* __restrict__ t3)
{
  __shared__ float tile[64][65];  // +1 pad: conflict-free column reads
  const int z = blockIdx.z;
  const float* W = z == 0 ? w0 : (z == 1 ? w1 : (z == 2 ? w2 : w3));
  bf16_t* Wt     = z == 0 ? t0 : (z == 1 ? t1 : (z == 2 ? t2 : t3));
  const int tid = threadIdx.x;
  const int kb = blockIdx.y * 64, nb = blockIdx.x * 64;
#pragma unroll
  for (int j = 0; j < 16; j++) {
    int flat = j * 256 + tid;
    int kr = flat >> 6, nc = flat & 63;
    tile[kr][nc] = W[(size_t)(kb + kr) * D_MOD + nb + nc];
  }
  __syncthreads();
#pragma unroll
  for (int j = 0; j < 16; j++) {
    int flat = j * 256 + tid;
    int nr = flat >> 6, kc = flat & 63;
    Wt[(size_t)(nb + nr) * D_MOD + kb + kc] = (bf16_t)tile[kc][nr];
  }
}

// ---------------- GEMM core: C[128x128] = A[128xK] * Bt[128xK]^T, K=1024, BK=64 ----------------
// A row-major [M][1024] bf16; Bt row-major [N][1024] bf16 (i.e. W^T). 4 waves, 64x64 each.
__device__ __forceinline__ void gemm_core(const bf16_t* __restrict__ A,
                                          const bf16_t* __restrict__ Bt,
                                          bf16_t* As, bf16_t* Bs,
                                          int mbase, int nbase, f32x4 acc[4][4])
{
  const int tid = threadIdx.x;
  const int lane = tid & 63, wave = tid >> 6;
  const int lrow = lane & 15, lg = lane >> 4;
  const int wm = wave >> 1, wn = wave & 1;
  for (int kt = 0; kt < D_MOD; kt += 64) {
    __syncthreads();  // previous compute done before overwrite
#pragma unroll
    for (int j = 0; j < 4; j++) {
      int flat = j * 256 + tid;          // 0..1023
      int r = flat >> 3, c8 = flat & 7;  // row, 16B block
      gload_lds16(A  + (size_t)(mbase + r) * D_MOD + kt + c8 * 8, As + flat * 8);
      gload_lds16(Bt + (size_t)(nbase + r) * D_MOD + kt + c8 * 8, Bs + flat * 8);
    }
    __syncthreads();  // compiler drains vmcnt before barrier
#pragma unroll
    for (int kc = 0; kc < 2; kc++) {
      bf16x8 af[4], bfr[4];
#pragma unroll
      for (int mt = 0; mt < 4; mt++)
        af[mt] = *(const bf16x8*)(As + (wm * 64 + mt * 16 + lrow) * 64 + kc * 32 + lg * 8);
#pragma unroll
      for (int nt = 0; nt < 4; nt++)
        bfr[nt] = *(const bf16x8*)(Bs + (wn * 64 + nt * 16 + lrow) * 64 + kc * 32 + lg * 8);
#pragma unroll
      for (int mt = 0; mt < 4; mt++)
#pragma unroll
        for (int nt = 0; nt < 4; nt++)
          acc[mt][nt] = mfma16(af[mt], bfr[nt], acc[mt][nt]);
    }
  }
}

// ---------------- fused QKV projection ----------------
// z=0: Q -> Qp[M][D]; z=1: K -> Kp[M][D]; z=2: V -> Vt[b][h][64][S] (transposed for PV B-frags)
__global__ __launch_bounds__(256) void gemm_qkv_kernel(
    const bf16_t* __restrict__ Xq, const bf16_t* __restrict__ Xk, const bf16_t* __restrict__ Xv,
    const bf16_t* __restrict__ WqT, const bf16_t* __restrict__ WkT, const bf16_t* __restrict__ WvT,
    const float* __restrict__ bq, const float* __restrict__ bk, const float* __restrict__ bv,
    bf16_t* __restrict__ Qp, bf16_t* __restrict__ Kp, bf16_t* __restrict__ Vt)
{
  __shared__ __align__(16) bf16_t As[128 * 64];
  __shared__ __align__(16) bf16_t Bs[128 * 64];
  const int z = blockIdx.z;
  const bf16_t* A    = z == 0 ? Xq  : (z == 1 ? Xk  : Xv);
  const bf16_t* Bt   = z == 0 ? WqT : (z == 1 ? WkT : WvT);
  const float*  bias = z == 0 ? bq  : (z == 1 ? bk  : bv);
  f32x4 acc[4][4] = {};
  const int mbase = blockIdx.y * 128, nbase = blockIdx.x * 128;
  gemm_core(A, Bt, As, Bs, mbase, nbase, acc);
  const int tid = threadIdx.x, lane = tid & 63, wave = tid >> 6;
  const int lrow = lane & 15, lg = lane >> 4, wm = wave >> 1, wn = wave & 1;
  if (z < 2) {
    bf16_t* Out = z == 0 ? Qp : Kp;
#pragma unroll
    for (int mt = 0; mt < 4; mt++) {
      int r0 = mbase + wm * 64 + mt * 16 + lg * 4;
#pragma unroll
      for (int nt = 0; nt < 4; nt++) {
        int col = nbase + wn * 64 + nt * 16 + lrow;
        float bb = bias[col];
#pragma unroll
        for (int r = 0; r < 4; r++)
          Out[(size_t)(r0 + r) * D_MOD + col] = (bf16_t)(acc[mt][nt][r] + bb);
      }
    }
  } else {
#pragma unroll
    for (int mt = 0; mt < 4; mt++) {
      int r0 = mbase + wm * 64 + mt * 16 + lg * 4;
      int b = r0 >> 11, s0 = r0 & (S_LEN - 1);  // 4 consecutive s, same b
#pragma unroll
      for (int nt = 0; nt < 4; nt++) {
        int col = nbase + wn * 64 + nt * 16 + lrow;  // h*64+hd
        float bb = bias[col];
        bf16x4 pk;
#pragma unroll
        for (int r = 0; r < 4; r++) pk[r] = (bf16_t)(acc[mt][nt][r] + bb);
        *(bf16x4*)(Vt + ((size_t)(b * NHEAD + (col >> 6)) * 64 + (col & 63)) * S_LEN + s0) = pk;
      }
    }
  }
}

// ---------------- flash attention v4: barrier-free, K/V direct from L2 ----------------
// Block: 4 independent waves x 32 q-rows. No K/V LDS staging (K+V per head = 512 KB,
// L2-resident; grid maps all 16 blocks of a head onto one XCD so its L2 holds 4 heads).
// Swapped QK^T (S^T: lane owns one q-row -> in-register softmax). Defer-max (T13).
// Hand pipeline: V issued at iter top (hidden under QK^T+softmax); next-iter K issued
// right after QK^T consumes current K (2x-unrolled static double buffer).
__global__ __launch_bounds__(256) void attn_kernel(
    const bf16_t* __restrict__ Q, const bf16_t* __restrict__ K,
    const bf16_t* __restrict__ Vt, bf16_t* __restrict__ O)
{
  __shared__ __align__(16) bf16_t plds[4][32 * 72];  // per-wave P relay only
  const int tid = threadIdx.x, wave = tid >> 6, lane = tid & 63;
  const int lrow = lane & 15, lg = lane >> 4;
  const int bh = blockIdx.x;             // head fastest: linear id = qx*32+bh, 32%8==0
  const int b = bh >> 4, h = bh & 15;    //  -> XCD = bh&7 (all blocks of a head share L2)
  const int qbase = blockIdx.y * 128 + wave * 32;
  const bf16_t* Kb = K + (size_t)(b * S_LEN) * D_MOD + h * 64;
  const bf16_t* Vb = Vt + (size_t)bh * 64 * S_LEN;

  // Q fragments: 2 row-blocks x 2 k-chunks (lane&15 = q-row within block)
  bf16x8 qf[2][2];
#pragma unroll
  for (int qr = 0; qr < 2; qr++) {
    const bf16_t* Qrow = Q + (size_t)(b * S_LEN + qbase + qr * 16 + lrow) * D_MOD + h * 64;
    qf[qr][0] = *(const bf16x8*)(Qrow + lg * 8);
    qf[qr][1] = *(const bf16x8*)(Qrow + 32 + lg * 8);
  }

  float mrow[2] = {-1e30f, -1e30f};  // softmax layout: this lane's q = qr*16+lrow
  float lsum[2] = {0.f, 0.f};
  f32x4 oacc[2][4] = {};             // PV C-layout: rows q = lg*4+r, cols d = nt*16+lrow

  bf16_t* pl = (bf16_t*)plds[wave];
  const float sc2 = 0.03125f * 1.44269504f;  // (1/sqrt(D)) * log2(e)

  auto load_k = [&](bf16x8 (&kf)[4][2], int kt) {
#pragma unroll
    for (int ct = 0; ct < 4; ct++) {
      const bf16_t* Krow = Kb + (size_t)(kt + ct * 16 + lrow) * D_MOD;
      kf[ct][0] = *(const bf16x8*)(Krow + lg * 8);
      kf[ct][1] = *(const bf16x8*)(Krow + 32 + lg * 8);
    }
  };

  auto iter = [&](bf16x8 (&kfc)[4][2], bf16x8 (&kfn)[4][2], int kt, bool prefetch) {
    // ---- V loads for THIS iter issued first: latency hides under QK^T + softmax ----
    bf16x8 vf[4][2];
#pragma unroll
    for (int nt = 0; nt < 4; nt++) {
      const bf16_t* Vrow = Vb + (size_t)(nt * 16 + lrow) * S_LEN + kt;
      vf[nt][0] = *(const bf16x8*)(Vrow + lg * 8);
      vf[nt][1] = *(const bf16x8*)(Vrow + 32 + lg * 8);
    }

    // ---- QK^T (swapped): st = S^T tile; 16 MFMA ----
    f32x4 st[2][4] = {};
    __builtin_amdgcn_s_setprio(1);
#pragma unroll
    for (int qr = 0; qr < 2; qr++)
#pragma unroll
      for (int ct = 0; ct < 4; ct++) {
        st[qr][ct] = mfma16(kfc[ct][0], qf[qr][0], st[qr][ct]);
        st[qr][ct] = mfma16(kfc[ct][1], qf[qr][1], st[qr][ct]);
      }
    __builtin_amdgcn_s_setprio(0);

    // ---- next-iter K loads: kfc consumed, issue into the other buffer ----
    if (prefetch) load_k(kfn, kt + 64);

    // ---- online softmax, defer-max: lane owns row q = qr*16+lrow ----
#pragma unroll
    for (int qr = 0; qr < 2; qr++) {
      f32x4 mm;
#pragma unroll
      for (int r = 0; r < 4; r++)
        mm[r] = fmaxf(fmaxf(st[qr][0][r], st[qr][1][r]), fmaxf(st[qr][2][r], st[qr][3][r]));
      float rmax = fmaxf(fmaxf(mm[0], mm[1]), fmaxf(mm[2], mm[3]));
      rmax = fmaxf(rmax, __shfl_xor(rmax, 16));
      rmax = fmaxf(rmax, __shfl_xor(rmax, 32));
      float nm = rmax * sc2;
      if (!__all(nm <= mrow[qr] + 8.f)) {   // rare: rescale path
        float mn = fmaxf(mrow[qr], nm);
        float corr = __builtin_amdgcn_exp2f(mrow[qr] - mn);
        mrow[qr] = mn;
        lsum[qr] *= corr;
        float cpv[4];
#pragma unroll
        for (int r = 0; r < 4; r++) cpv[r] = __shfl(corr, lg * 4 + r);
#pragma unroll
        for (int nt = 0; nt < 4; nt++)
#pragma unroll
          for (int r = 0; r < 4; r++) oacc[qr][nt][r] *= cpv[r];
      }
      float rsum = 0.f;
#pragma unroll
      for (int ct = 0; ct < 4; ct++)
#pragma unroll
        for (int r = 0; r < 4; r++) {
          float pv = __builtin_amdgcn_exp2f(__builtin_fmaf(st[qr][ct][r], sc2, -mrow[qr]));
          st[qr][ct][r] = pv;
          rsum += pv;
        }
      rsum += __shfl_xor(rsum, 16);
      rsum += __shfl_xor(rsum, 32);
      lsum[qr] += rsum;
      // P write: row q = qr*16+lrow, k = ct*16 + lg*4 + r -> one b64 per ct
#pragma unroll
      for (int ct = 0; ct < 4; ct++) {
        bf16x4 pk;
#pragma unroll
        for (int r = 0; r < 4; r++) pk[r] = (bf16_t)st[qr][ct][r];
        *(bf16x4*)(pl + (qr * 16 + lrow) * 72 + ct * 16 + lg * 4) = pk;
      }
    }

    // ---- PV: af from same-wave LDS relay (in-order DS pipe, no barrier) ----
    __builtin_amdgcn_s_setprio(1);
#pragma unroll
    for (int qr = 0; qr < 2; qr++)
#pragma unroll
      for (int kc = 0; kc < 2; kc++) {
        bf16x8 af = *(const bf16x8*)(pl + (qr * 16 + lrow) * 72 + kc * 32 + lg * 8);
#pragma unroll
        for (int nt = 0; nt < 4; nt++)
          oacc[qr][nt] = mfma16(af, vf[nt][kc], oacc[qr][nt]);
      }
    __builtin_amdgcn_s_setprio(0);
  };

  bf16x8 kfA[4][2], kfB[4][2];
  load_k(kfA, 0);
#pragma unroll 1
  for (int kt = 0; kt < S_LEN; kt += 128) {   // 2x unrolled: static K double-buffer
    iter(kfA, kfB, kt, true);
    iter(kfB, kfA, kt + 64, kt + 128 < S_LEN);
  }

  bf16_t* Or = O + (size_t)(b * S_LEN + qbase) * D_MOD + h * 64;
#pragma unroll
  for (int qr = 0; qr < 2; qr++) {
    float linv[4];
#pragma unroll
    for (int r = 0; r < 4; r++)
      linv[r] = 1.f / __shfl(lsum[qr], lg * 4 + r);
#pragma unroll
    for (int r = 0; r < 4; r++)
#pragma unroll
      for (int nt = 0; nt < 4; nt++)
        Or[(size_t)(qr * 16 + lg * 4 + r) * D_MOD + nt * 16 + lrow] = (bf16_t)(oacc[qr][nt][r] * linv[r]);
  }
}

// ---------------- output projection: fp32 out ----------------
__global__ __launch_bounds__(256) void gemm_o_kernel(
    const bf16_t* __restrict__ A, const bf16_t* __restrict__ Bt,
    const float* __restrict__ bias, float* __restrict__ Out)
{
  __shared__ __align__(16) bf16_t As[128 * 64];
  __shared__ __align__(16) bf16_t Bs[128 * 64];
  f32x4 acc[4][4] = {};
  const int mbase = blockIdx.y * 128, nbase = blockIdx.x * 128;
  gemm_core(A, Bt, As, Bs, mbase, nbase, acc);
  const int tid = threadIdx.x, lane = tid & 63, wave = tid >> 6;
  const int lrow = lane & 15, lg = lane >> 4, wm = wave >> 1, wn = wave & 1;
#pragma unroll
  for (int mt = 0; mt < 4; mt++) {
    int r0 = mbase + wm * 64 + mt * 16 + lg * 4;
#pragma unroll
    for (int nt = 0; nt < 4; nt++) {
      int col = nbase + wn * 64 + nt * 16 + lrow;
      float bb = bias[col];
#pragma unroll
      for (int r = 0; r < 4; r++)
        Out[(size_t)(r0 + r) * D_MOD + col] = acc[mt][nt][r] + bb;
    }
  }
}

extern "C" void kernel_launch(void* const* d_in, const int* in_sizes, int n_in,
                              void* d_out, int out_size, void* d_ws, size_t ws_size,
                              hipStream_t stream) {
  const float* q  = (const float*)d_in[0];
  const float* k  = (const float*)d_in[1];
  const float* v  = (const float*)d_in[2];
  const float* Wq = (const float*)d_in[3];
  const float* bq = (const float*)d_in[4];
  const float* Wk = (const float*)d_in[5];
  const float* bk = (const float*)d_in[6];
  const float* Wv = (const float*)d_in[7];
  const float* bv = (const float*)d_in[8];
  const float* Wo = (const float*)d_in[9];
  const float* bo = (const float*)d_in[10];
  float* out = (float*)d_out;

  char* ws = (char*)d_ws;
  const size_t MB = 1024 * 1024;
  bf16_t* Xq  = (bf16_t*)(ws + 0 * MB);   // 8 MB each
  bf16_t* Xk  = (bf16_t*)(ws + 8 * MB);
  bf16_t* Xv  = (bf16_t*)(ws + 16 * MB);
  bf16_t* WqT = (bf16_t*)(ws + 24 * MB);  // 2 MB each
  bf16_t* WkT = (bf16_t*)(ws + 26 * MB);
  bf16_t* WvT = (bf16_t*)(ws + 28 * MB);
  bf16_t* WoT = (bf16_t*)(ws + 30 * MB);
  bf16_t* Qp  = (bf16_t*)(ws + 32 * MB);
  bf16_t* Kp  = (bf16_t*)(ws + 40 * MB);
  bf16_t* Vt  = (bf16_t*)(ws + 48 * MB);
  bf16_t* AO  = (bf16_t*)(ws + 0 * MB);   // reuse Xq (consumed before attn)

  dim3 cb(256);
  cvt3_kernel<<<dim3(4096, 1, 3), cb, 0, stream>>>(q, k, v, Xq, Xk, Xv);
  wtrans_kernel<<<dim3(16, 16, 4), cb, 0, stream>>>(Wq, Wk, Wv, Wo, WqT, WkT, WvT, WoT);
  gemm_qkv_kernel<<<dim3(8, 32, 3), cb, 0, stream>>>(Xq, Xk, Xv, WqT, WkT, WvT,
                                                     bq, bk, bv, Qp, Kp, Vt);
  attn_kernel<<<dim3(32, 16), cb, 0, stream>>>(Qp, Kp, Vt, AO);
  gemm_o_kernel<<<dim3(8, 32), cb, 0, stream>>>(AO, WoT, bo, out);
}

// Round 7
// 262.882 us; speedup vs baseline: 1.1989x; 1.1989x over previous
//
#include <hip/hip_runtime.h>
#include <hip/hip_bf16.h>
#include <stdint.h>

#define S_LEN 2048
#define D_MOD 1024
#define NHEAD 16
#define BATCH 2
#define M_TOT (BATCH * S_LEN)  // 4096

typedef __bf16 bf16_t;
typedef __bf16 bf16x8 __attribute__((ext_vector_type(8)));
typedef __bf16 bf16x4 __attribute__((ext_vector_type(4)));
typedef float f32x4 __attribute__((ext_vector_type(4)));

typedef __attribute__((address_space(1))) void gas_void;
typedef __attribute__((address_space(3))) void las_void;

__device__ __forceinline__ void gload_lds16(const void* g, void* l) {
#if defined(__has_builtin) && __has_builtin(__builtin_amdgcn_global_load_lds)
  __builtin_amdgcn_global_load_lds((gas_void*)g, (las_void*)l, 16u, 0, 0u);
#else
  *(bf16x8*)l = *(const bf16x8*)g;
#endif
}

__device__ __forceinline__ f32x4 mfma16(bf16x8 a, bf16x8 b, f32x4 c) {
  return __builtin_amdgcn_mfma_f32_16x16x32_bf16(a, b, c, 0, 0, 0);
}

// ---------------- fp32 -> bf16 convert (queries/keys/values), float4 per thread ----------------
__global__ __launch_bounds__(256) void cvt3_kernel(
    const float* __restrict__ a, const float* __restrict__ b, const float* __restrict__ c,
    bf16_t* __restrict__ oa, bf16_t* __restrict__ ob, bf16_t* __restrict__ oc)
{
  const float* in  = blockIdx.z == 0 ? a : (blockIdx.z == 1 ? b : c);
  bf16_t*      out = blockIdx.z == 0 ? oa : (blockIdx.z == 1 ? ob : oc);
  int i = blockIdx.x * 256 + threadIdx.x;
  float4 v = ((const float4*)in)[i];
  bf16x4 o;
  o[0] = (bf16_t)v.x; o[1] = (bf16_t)v.y; o[2] = (bf16_t)v.z; o[3] = (bf16_t)v.w;
  ((bf16x4*)out)[i] = o;
}

// ---------------- weight transpose + convert: W[K][N] f32 -> Wt[N][K] bf16 ----------------
__global__ __launch_bounds__(256) void wtrans_kernel(
    const float* __restrict__ w0, const float* __restrict__ w1,
    const float* __restrict__ w2, const float* __restrict__ w3,
    bf16_t* __restrict__ t0, bf16_t* __restrict__ t1,
    bf16_t* __restrict__ t2, bf16_t* __restrict__ t3)
{
  __shared__ float tile[64][65];  // +1 pad: conflict-free column reads
  const int z = blockIdx.z;
  const float* W = z == 0 ? w0 : (z == 1 ? w1 : (z == 2 ? w2 : w3));
  bf16_t* Wt     = z == 0 ? t0 : (z == 1 ? t1 : (z == 2 ? t2 : t3));
  const int tid = threadIdx.x;
  const int kb = blockIdx.y * 64, nb = blockIdx.x * 64;
#pragma unroll
  for (int j = 0; j < 16; j++) {
    int flat = j * 256 + tid;
    int kr = flat >> 6, nc = flat & 63;
    tile[kr][nc] = W[(size_t)(kb + kr) * D_MOD + nb + nc];
  }
  __syncthreads();
#pragma unroll
  for (int j = 0; j < 16; j++) {
    int flat = j * 256 + tid;
    int nr = flat >> 6, kc = flat & 63;
    Wt[(size_t)(nb + nr) * D_MOD + kb + kc] = (bf16_t)tile[kc][nr];
  }
}

// ---------------- GEMM core: C[128x128] = A[128xK] * Bt[128xK]^T, K=1024, BK=64 ----------------
// A row-major [M][1024] bf16; Bt row-major [N][1024] bf16 (i.e. W^T). 4 waves, 64x64 each.
// LDS tiles XOR-swizzled (rule 21: linear gload_lds dest + pre-swizzled SOURCE chunk,
// same XOR on fragment reads): kills the 16-way bank conflict of 128-B row stride.
__device__ __forceinline__ void gemm_core(const bf16_t* __restrict__ A,
                                          const bf16_t* __restrict__ Bt,
                                          bf16_t* As, bf16_t* Bs,
                                          int mbase, int nbase, f32x4 acc[4][4])
{
  const int tid = threadIdx.x;
  const int lane = tid & 63, wave = tid >> 6;
  const int lrow = lane & 15, lg = lane >> 4;
  const int wm = wave >> 1, wn = wave & 1;
  const int rs = lrow & 7;  // read-side swizzle key (row & 7)
  for (int kt = 0; kt < D_MOD; kt += 64) {
    __syncthreads();  // previous compute done before overwrite
#pragma unroll
    for (int j = 0; j < 4; j++) {
      int flat = j * 256 + tid;          // 0..1023
      int r = flat >> 3, c8 = flat & 7;  // row, 16B chunk
      int sc8 = c8 ^ (r & 7);            // pre-swizzled SOURCE chunk
      gload_lds16(A  + (size_t)(mbase + r) * D_MOD + kt + sc8 * 8, As + flat * 8);
      gload_lds16(Bt + (size_t)(nbase + r) * D_MOD + kt + sc8 * 8, Bs + flat * 8);
    }
    __syncthreads();  // compiler drains vmcnt before barrier
#pragma unroll
    for (int kc = 0; kc < 2; kc++) {
      bf16x8 af[4], bfr[4];
#pragma unroll
      for (int mt = 0; mt < 4; mt++)
        af[mt] = *(const bf16x8*)(As + (wm * 64 + mt * 16 + lrow) * 64 + ((kc * 4 + lg) ^ rs) * 8);
#pragma unroll
      for (int nt = 0; nt < 4; nt++)
        bfr[nt] = *(const bf16x8*)(Bs + (wn * 64 + nt * 16 + lrow) * 64 + ((kc * 4 + lg) ^ rs) * 8);
#pragma unroll
      for (int mt = 0; mt < 4; mt++)
#pragma unroll
        for (int nt = 0; nt < 4; nt++)
          acc[mt][nt] = mfma16(af[mt], bfr[nt], acc[mt][nt]);
    }
  }
}

// ---------------- fused QKV projection ----------------
// z=0: Q -> Qp[M][D]; z=1: K -> Kp[M][D]; z=2: V -> Vt[b][h][64][S] (transposed for PV B-frags)
__global__ __launch_bounds__(256) void gemm_qkv_kernel(
    const bf16_t* __restrict__ Xq, const bf16_t* __restrict__ Xk, const bf16_t* __restrict__ Xv,
    const bf16_t* __restrict__ WqT, const bf16_t* __restrict__ WkT, const bf16_t* __restrict__ WvT,
    const float* __restrict__ bq, const float* __restrict__ bk, const float* __restrict__ bv,
    bf16_t* __restrict__ Qp, bf16_t* __restrict__ Kp, bf16_t* __restrict__ Vt)
{
  __shared__ __align__(16) bf16_t As[128 * 64];
  __shared__ __align__(16) bf16_t Bs[128 * 64];
  const int z = blockIdx.z;
  const bf16_t* A    = z == 0 ? Xq  : (z == 1 ? Xk  : Xv);
  const bf16_t* Bt   = z == 0 ? WqT : (z == 1 ? WkT : WvT);
  const float*  bias = z == 0 ? bq  : (z == 1 ? bk  : bv);
  f32x4 acc[4][4] = {};
  const int mbase = blockIdx.y * 128, nbase = blockIdx.x * 128;
  gemm_core(A, Bt, As, Bs, mbase, nbase, acc);
  const int tid = threadIdx.x, lane = tid & 63, wave = tid >> 6;
  const int lrow = lane & 15, lg = lane >> 4, wm = wave >> 1, wn = wave & 1;
  if (z < 2) {
    bf16_t* Out = z == 0 ? Qp : Kp;
#pragma unroll
    for (int mt = 0; mt < 4; mt++) {
      int r0 = mbase + wm * 64 + mt * 16 + lg * 4;
#pragma unroll
      for (int nt = 0; nt < 4; nt++) {
        int col = nbase + wn * 64 + nt * 16 + lrow;
        float bb = bias[col];
#pragma unroll
        for (int r = 0; r < 4; r++)
          Out[(size_t)(r0 + r) * D_MOD + col] = (bf16_t)(acc[mt][nt][r] + bb);
      }
    }
  } else {
#pragma unroll
    for (int mt = 0; mt < 4; mt++) {
      int r0 = mbase + wm * 64 + mt * 16 + lg * 4;
      int b = r0 >> 11, s0 = r0 & (S_LEN - 1);  // 4 consecutive s, same b
#pragma unroll
      for (int nt = 0; nt < 4; nt++) {
        int col = nbase + wn * 64 + nt * 16 + lrow;  // h*64+hd
        float bb = bias[col];
        bf16x4 pk;
#pragma unroll
        for (int r = 0; r < 4; r++) pk[r] = (bf16_t)(acc[mt][nt][r] + bb);
        *(bf16x4*)(Vt + ((size_t)(b * NHEAD + (col >> 6)) * 64 + (col & 63)) * S_LEN + s0) = pk;
      }
    }
  }
}

// ---------------- flash attention v3 (proven 85 us): swapped QK^T, LDS-staged K/V ----------------
// Block: 4 waves x 32 q-rows = 128 q-rows. K/V tiles staged via global_load_lds,
// XOR-swizzled, double-buffered, one barrier/iter.
// QK^T computed as mfma(K,Q) -> S^T: lane (lrow,lg) holds S[q=lrow][k=ct*16+lg*4+r].
// Row reduce = in-reg ops + shfl_xor(16,32). P written as bf16x4 (ds_write_b64).
__global__ __launch_bounds__(256) void attn_kernel(
    const bf16_t* __restrict__ Q, const bf16_t* __restrict__ K,
    const bf16_t* __restrict__ Vt, bf16_t* __restrict__ O)
{
  __shared__ __align__(16) bf16_t Ks[2][64 * 64];
  __shared__ __align__(16) bf16_t Vs[2][64 * 64];
  __shared__ __align__(16) bf16_t plds[4][32 * 72];  // per-wave P relay, padded rows
  const int tid = threadIdx.x, wave = tid >> 6, lane = tid & 63;
  const int lrow = lane & 15, lg = lane >> 4;
  const int bh = blockIdx.y;             // 0..31
  const int b = bh >> 4, h = bh & 15;
  const int qbase = blockIdx.x * 128 + wave * 32;
  const bf16_t* Kb = K + (size_t)(b * S_LEN) * D_MOD + h * 64;
  const bf16_t* Vb = Vt + (size_t)bh * 64 * S_LEN;

  // Q fragments: 2 row-blocks x 2 k-chunks (lane&15 = q-row within block)
  bf16x8 qf[2][2];
#pragma unroll
  for (int qr = 0; qr < 2; qr++) {
    const bf16_t* Qrow = Q + (size_t)(b * S_LEN + qbase + qr * 16 + lrow) * D_MOD + h * 64;
    qf[qr][0] = *(const bf16x8*)(Qrow + lg * 8);
    qf[qr][1] = *(const bf16x8*)(Qrow + 32 + lg * 8);
  }

  float mrow[2] = {-1e30f, -1e30f};  // softmax-layout state: this lane's q = qr*16+lrow
  float lsum[2] = {0.f, 0.f};
  f32x4 oacc[2][4] = {};             // PV C-layout: rows q = lg*4+r, cols d = nt*16+lrow

  bf16_t* pl = (bf16_t*)plds[wave];
  const float sc2 = 0.03125f * 1.44269504f;  // (1/sqrt(D)) * log2(e)
  const int rs = lrow & 7;                   // read-side XOR swizzle key

  auto stage = [&](int buf, int kt) {
#pragma unroll
    for (int j = 0; j < 2; j++) {
      int flat = j * 256 + tid;                 // 0..511
      int r = flat >> 3, c8 = flat & 7;
      int sc8 = c8 ^ (r & 7);                   // pre-swizzled SOURCE chunk
      gload_lds16(Kb + (size_t)(kt + r) * D_MOD + sc8 * 8, &Ks[buf][flat * 8]);
    }
#pragma unroll
    for (int j = 0; j < 2; j++) {
      int flat = j * 256 + tid;
      int r = flat >> 3, c8 = flat & 7;
      int sc8 = c8 ^ (r & 7);
      gload_lds16(Vb + (size_t)r * S_LEN + kt + sc8 * 8, &Vs[buf][flat * 8]);
    }
  };

  stage(0, 0);
  __syncthreads();  // drain vmcnt: buffer 0 ready

  for (int kt = 0; kt < S_LEN; kt += 64) {
    const int cur = (kt >> 6) & 1;
    if (kt + 64 < S_LEN) stage(cur ^ 1, kt + 64);  // async prefetch overlaps compute
    const bf16_t* Kc = Ks[cur];
    const bf16_t* Vc = Vs[cur];

    // ---- QK^T (swapped): st[qr][ct] = S^T tile; 16 MFMA ----
    bf16x8 kf[4][2];
#pragma unroll
    for (int ct = 0; ct < 4; ct++) {
      int row = ct * 16 + lrow;
      kf[ct][0] = *(const bf16x8*)(Kc + row * 64 + ((lg) ^ rs) * 8);
      kf[ct][1] = *(const bf16x8*)(Kc + row * 64 + ((4 + lg) ^ rs) * 8);
    }
    f32x4 st[2][4] = {};
    __builtin_amdgcn_s_setprio(1);
#pragma unroll
    for (int qr = 0; qr < 2; qr++)
#pragma unroll
      for (int ct = 0; ct < 4; ct++) {
        st[qr][ct] = mfma16(kf[ct][0], qf[qr][0], st[qr][ct]);
        st[qr][ct] = mfma16(kf[ct][1], qf[qr][1], st[qr][ct]);
      }
    __builtin_amdgcn_s_setprio(0);

    // ---- online softmax: each lane owns row q = qr*16+lrow ----
    float corr_pv[2][4];
#pragma unroll
    for (int qr = 0; qr < 2; qr++) {
      f32x4 m01, m23, mm;
#pragma unroll
      for (int r = 0; r < 4; r++) {
        m01[r] = fmaxf(st[qr][0][r], st[qr][1][r]);
        m23[r] = fmaxf(st[qr][2][r], st[qr][3][r]);
        mm[r] = fmaxf(m01[r], m23[r]);
      }
      float rmax = fmaxf(fmaxf(mm[0], mm[1]), fmaxf(mm[2], mm[3]));
      rmax = fmaxf(rmax, __shfl_xor(rmax, 16));
      rmax = fmaxf(rmax, __shfl_xor(rmax, 32));
      float mn = fmaxf(mrow[qr], rmax * sc2);
      float corr = __builtin_amdgcn_exp2f(mrow[qr] - mn);
      mrow[qr] = mn;
      f32x4 p[4];
      f32x4 ps;
#pragma unroll
      for (int r = 0; r < 4; r++) {
        p[0][r] = __builtin_amdgcn_exp2f(__builtin_fmaf(st[qr][0][r], sc2, -mn));
        p[1][r] = __builtin_amdgcn_exp2f(__builtin_fmaf(st[qr][1][r], sc2, -mn));
        p[2][r] = __builtin_amdgcn_exp2f(__builtin_fmaf(st[qr][2][r], sc2, -mn));
        p[3][r] = __builtin_amdgcn_exp2f(__builtin_fmaf(st[qr][3][r], sc2, -mn));
        ps[r] = (p[0][r] + p[1][r]) + (p[2][r] + p[3][r]);
      }
      float rsum = (ps[0] + ps[1]) + (ps[2] + ps[3]);
      rsum += __shfl_xor(rsum, 16);
      rsum += __shfl_xor(rsum, 32);
      lsum[qr] = lsum[qr] * corr + rsum;
      // P write: row q = qr*16+lrow, k = ct*16 + lg*4 + r -> one b64 per ct
#pragma unroll
      for (int ct = 0; ct < 4; ct++) {
        bf16x4 pk;
#pragma unroll
        for (int r = 0; r < 4; r++) pk[r] = (bf16_t)p[ct][r];
        *(bf16x4*)(pl + (qr * 16 + lrow) * 72 + ct * 16 + lg * 4) = pk;
      }
      // rescale factors for PV layout (row q = lg*4+r): fetch from lane lg*4+r
#pragma unroll
      for (int r = 0; r < 4; r++)
        corr_pv[qr][r] = __shfl(corr, lg * 4 + r);
    }
#pragma unroll
    for (int qr = 0; qr < 2; qr++)
#pragma unroll
      for (int nt = 0; nt < 4; nt++)
#pragma unroll
        for (int r = 0; r < 4; r++)
          oacc[qr][nt][r] *= corr_pv[qr][r];

    // ---- PV: V-frags read once, reused for both q row-blocks ----
    bf16x8 vf[4][2];
#pragma unroll
    for (int nt = 0; nt < 4; nt++) {
      int row = nt * 16 + lrow;
      vf[nt][0] = *(const bf16x8*)(Vc + row * 64 + ((lg) ^ rs) * 8);
      vf[nt][1] = *(const bf16x8*)(Vc + row * 64 + ((4 + lg) ^ rs) * 8);
    }
    __builtin_amdgcn_s_setprio(1);
#pragma unroll
    for (int qr = 0; qr < 2; qr++)
#pragma unroll
      for (int kc = 0; kc < 2; kc++) {
        bf16x8 af = *(const bf16x8*)(pl + (qr * 16 + lrow) * 72 + kc * 32 + lg * 8);
#pragma unroll
        for (int nt = 0; nt < 4; nt++)
          oacc[qr][nt] = mfma16(af, vf[nt][kc], oacc[qr][nt]);
      }
    __builtin_amdgcn_s_setprio(0);

    __syncthreads();  // waves done with `cur`; prefetch of cur^1 drained
  }

  bf16_t* Or = O + (size_t)(b * S_LEN + qbase) * D_MOD + h * 64;
#pragma unroll
  for (int qr = 0; qr < 2; qr++) {
    float linv[4];
#pragma unroll
    for (int r = 0; r < 4; r++)
      linv[r] = 1.f / __shfl(lsum[qr], lg * 4 + r);
#pragma unroll
    for (int r = 0; r < 4; r++)
#pragma unroll
      for (int nt = 0; nt < 4; nt++)
        Or[(size_t)(qr * 16 + lg * 4 + r) * D_MOD + nt * 16 + lrow] = (bf16_t)(oacc[qr][nt][r] * linv[r]);
  }
}

// ---------------- output projection: fp32 out ----------------
__global__ __launch_bounds__(256) void gemm_o_kernel(
    const bf16_t* __restrict__ A, const bf16_t* __restrict__ Bt,
    const float* __restrict__ bias, float* __restrict__ Out)
{
  __shared__ __align__(16) bf16_t As[128 * 64];
  __shared__ __align__(16) bf16_t Bs[128 * 64];
  f32x4 acc[4][4] = {};
  const int mbase = blockIdx.y * 128, nbase = blockIdx.x * 128;
  gemm_core(A, Bt, As, Bs, mbase, nbase, acc);
  const int tid = threadIdx.x, lane = tid & 63, wave = tid >> 6;
  const int lrow = lane & 15, lg = lane >> 4, wm = wave >> 1, wn = wave & 1;
#pragma unroll
  for (int mt = 0; mt < 4; mt++) {
    int r0 = mbase + wm * 64 + mt * 16 + lg * 4;
#pragma unroll
    for (int nt = 0; nt < 4; nt++) {
      int col = nbase + wn * 64 + nt * 16 + lrow;
      float bb = bias[col];
#pragma unroll
      for (int r = 0; r < 4; r++)
        Out[(size_t)(r0 + r) * D_MOD + col] = acc[mt][nt][r] + bb;
    }
  }
}

extern "C" void kernel_launch(void* const* d_in, const int* in_sizes, int n_in,
                              void* d_out, int out_size, void* d_ws, size_t ws_size,
                              hipStream_t stream) {
  const float* q  = (const float*)d_in[0];
  const float* k  = (const float*)d_in[1];
  const float* v  = (const float*)d_in[2];
  const float* Wq = (const float*)d_in[3];
  const float* bq = (const float*)d_in[4];
  const float* Wk = (const float*)d_in[5];
  const float* bk = (const float*)d_in[6];
  const float* Wv = (const float*)d_in[7];
  const float* bv = (const float*)d_in[8];
  const float* Wo = (const float*)d_in[9];
  const float* bo = (const float*)d_in[10];
  float* out = (float*)d_out;

  char* ws = (char*)d_ws;
  const size_t MB = 1024 * 1024;
  bf16_t* Xq  = (bf16_t*)(ws + 0 * MB);   // 8 MB each
  bf16_t* Xk  = (bf16_t*)(ws + 8 * MB);
  bf16_t* Xv  = (bf16_t*)(ws + 16 * MB);
  bf16_t* WqT = (bf16_t*)(ws + 24 * MB);  // 2 MB each
  bf16_t* WkT = (bf16_t*)(ws + 26 * MB);
  bf16_t* WvT = (bf16_t*)(ws + 28 * MB);
  bf16_t* WoT = (bf16_t*)(ws + 30 * MB);
  bf16_t* Qp  = (bf16_t*)(ws + 32 * MB);
  bf16_t* Kp  = (bf16_t*)(ws + 40 * MB);
  bf16_t* Vt  = (bf16_t*)(ws + 48 * MB);
  bf16_t* AO  = (bf16_t*)(ws + 0 * MB);   // reuse Xq (consumed before attn)

  dim3 cb(256);
  cvt3_kernel<<<dim3(4096, 1, 3), cb, 0, stream>>>(q, k, v, Xq, Xk, Xv);
  wtrans_kernel<<<dim3(16, 16, 4), cb, 0, stream>>>(Wq, Wk, Wv, Wo, WqT, WkT, WvT, WoT);
  gemm_qkv_kernel<<<dim3(8, 32, 3), cb, 0, stream>>>(Xq, Xk, Xv, WqT, WkT, WvT,
                                                     bq, bk, bv, Qp, Kp, Vt);
  attn_kernel<<<dim3(16, 32), cb, 0, stream>>>(Qp, Kp, Vt, AO);
  gemm_o_kernel<<<dim3(8, 32), cb, 0, stream>>>(AO, WoT, bo, out);
}

// Round 8
// 260.883 us; speedup vs baseline: 1.2081x; 1.0077x over previous
//
#include <hip/hip_runtime.h>
#include <hip/hip_bf16.h>
#include <stdint.h>

#define S_LEN 2048
#define D_MOD 1024
#define NHEAD 16
#define BATCH 2
#define M_TOT (BATCH * S_LEN)  // 4096

typedef __bf16 bf16_t;
typedef __bf16 bf16x8 __attribute__((ext_vector_type(8)));
typedef __bf16 bf16x4 __attribute__((ext_vector_type(4)));
typedef float f32x4 __attribute__((ext_vector_type(4)));

typedef __attribute__((address_space(1))) void gas_void;
typedef __attribute__((address_space(3))) void las_void;

__device__ __forceinline__ void gload_lds16(const void* g, void* l) {
#if defined(__has_builtin) && __has_builtin(__builtin_amdgcn_global_load_lds)
  __builtin_amdgcn_global_load_lds((gas_void*)g, (las_void*)l, 16u, 0, 0u);
#else
  *(bf16x8*)l = *(const bf16x8*)g;
#endif
}

__device__ __forceinline__ f32x4 mfma16(bf16x8 a, bf16x8 b, f32x4 c) {
  return __builtin_amdgcn_mfma_f32_16x16x32_bf16(a, b, c, 0, 0, 0);
}

// ---------------- fp32 -> bf16 convert (queries/keys/values), float4 per thread ----------------
__global__ __launch_bounds__(256) void cvt3_kernel(
    const float* __restrict__ a, const float* __restrict__ b, const float* __restrict__ c,
    bf16_t* __restrict__ oa, bf16_t* __restrict__ ob, bf16_t* __restrict__ oc)
{
  const float* in  = blockIdx.z == 0 ? a : (blockIdx.z == 1 ? b : c);
  bf16_t*      out = blockIdx.z == 0 ? oa : (blockIdx.z == 1 ? ob : oc);
  int i = blockIdx.x * 256 + threadIdx.x;
  float4 v = ((const float4*)in)[i];
  bf16x4 o;
  o[0] = (bf16_t)v.x; o[1] = (bf16_t)v.y; o[2] = (bf16_t)v.z; o[3] = (bf16_t)v.w;
  ((bf16x4*)out)[i] = o;
}

// ---------------- weight transpose + convert: W[K][N] f32 -> Wt[N][K] bf16 ----------------
__global__ __launch_bounds__(256) void wtrans_kernel(
    const float* __restrict__ w0, const float* __restrict__ w1,
    const float* __restrict__ w2, const float* __restrict__ w3,
    bf16_t* __restrict__ t0, bf16_t* __restrict__ t1,
    bf16_t* __restrict__ t2, bf16_t* __restrict__ t3)
{
  __shared__ float tile[64][65];  // +1 pad: conflict-free column reads
  const int z = blockIdx.z;
  const float* W = z == 0 ? w0 : (z == 1 ? w1 : (z == 2 ? w2 : w3));
  bf16_t* Wt     = z == 0 ? t0 : (z == 1 ? t1 : (z == 2 ? t2 : t3));
  const int tid = threadIdx.x;
  const int kb = blockIdx.y * 64, nb = blockIdx.x * 64;
#pragma unroll
  for (int j = 0; j < 16; j++) {
    int flat = j * 256 + tid;
    int kr = flat >> 6, nc = flat & 63;
    tile[kr][nc] = W[(size_t)(kb + kr) * D_MOD + nb + nc];
  }
  __syncthreads();
#pragma unroll
  for (int j = 0; j < 16; j++) {
    int flat = j * 256 + tid;
    int nr = flat >> 6, kc = flat & 63;
    Wt[(size_t)(nb + nr) * D_MOD + kb + kc] = (bf16_t)tile[kc][nr];
  }
}

// ---------------- GEMM core v2: 2-phase single-barrier double-buffered ----------------
// C[128x128] = A[128xK] * Bt[128xK]^T, K=1024, BK=64. 4 waves, 64x64 each.
// Per K-step: stage(next tile) issued FIRST (async global_load_lds), then 32 MFMA from
// current buffer, then ONE __syncthreads (compiler's vmcnt-drain lands after compute ->
// staging latency hides under MFMA). LDS XOR-swizzled both-sides (rule 21).
__device__ __forceinline__ void gemm_core(const bf16_t* __restrict__ A,
                                          const bf16_t* __restrict__ Bt,
                                          bf16_t* As, bf16_t* Bs,   // each [2][128*64]
                                          int mbase, int nbase, f32x4 acc[4][4])
{
  const int tid = threadIdx.x;
  const int lane = tid & 63, wave = tid >> 6;
  const int lrow = lane & 15, lg = lane >> 4;
  const int wm = wave >> 1, wn = wave & 1;
  const int rs = lrow & 7;  // read-side swizzle key (row & 7)

  auto stage = [&](int buf, int kt) {
#pragma unroll
    for (int j = 0; j < 4; j++) {
      int flat = j * 256 + tid;          // 0..1023
      int r = flat >> 3, c8 = flat & 7;  // row, 16B chunk
      int sc8 = c8 ^ (r & 7);            // pre-swizzled SOURCE chunk
      gload_lds16(A  + (size_t)(mbase + r) * D_MOD + kt + sc8 * 8, As + buf * 8192 + flat * 8);
      gload_lds16(Bt + (size_t)(nbase + r) * D_MOD + kt + sc8 * 8, Bs + buf * 8192 + flat * 8);
    }
  };

  stage(0, 0);
  __syncthreads();  // drain: buffer 0 ready

  for (int kt = 0; kt < D_MOD; kt += 64) {
    const int cur = (kt >> 6) & 1;
    if (kt + 64 < D_MOD) stage(cur ^ 1, kt + 64);  // prefetch overlaps compute below
    const bf16_t* Ac = As + cur * 8192;
    const bf16_t* Bc = Bs + cur * 8192;
#pragma unroll
    for (int kc = 0; kc < 2; kc++) {
      bf16x8 af[4], bfr[4];
#pragma unroll
      for (int mt = 0; mt < 4; mt++)
        af[mt] = *(const bf16x8*)(Ac + (wm * 64 + mt * 16 + lrow) * 64 + ((kc * 4 + lg) ^ rs) * 8);
#pragma unroll
      for (int nt = 0; nt < 4; nt++)
        bfr[nt] = *(const bf16x8*)(Bc + (wn * 64 + nt * 16 + lrow) * 64 + ((kc * 4 + lg) ^ rs) * 8);
      __builtin_amdgcn_s_setprio(1);
#pragma unroll
      for (int mt = 0; mt < 4; mt++)
#pragma unroll
        for (int nt = 0; nt < 4; nt++)
          acc[mt][nt] = mfma16(af[mt], bfr[nt], acc[mt][nt]);
      __builtin_amdgcn_s_setprio(0);
    }
    __syncthreads();  // reads of cur done before next overwrite; prefetch drained
  }
}

// ---------------- fused QKV projection ----------------
// z=0: Q -> Qp[M][D]; z=1: K -> Kp[M][D]; z=2: V -> Vt[b][h][64][S] (transposed for PV B-frags)
__global__ __launch_bounds__(256) void gemm_qkv_kernel(
    const bf16_t* __restrict__ Xq, const bf16_t* __restrict__ Xk, const bf16_t* __restrict__ Xv,
    const bf16_t* __restrict__ WqT, const bf16_t* __restrict__ WkT, const bf16_t* __restrict__ WvT,
    const float* __restrict__ bq, const float* __restrict__ bk, const float* __restrict__ bv,
    bf16_t* __restrict__ Qp, bf16_t* __restrict__ Kp, bf16_t* __restrict__ Vt)
{
  __shared__ __align__(16) bf16_t As[2 * 128 * 64];
  __shared__ __align__(16) bf16_t Bs[2 * 128 * 64];
  const int z = blockIdx.z;
  const bf16_t* A    = z == 0 ? Xq  : (z == 1 ? Xk  : Xv);
  const bf16_t* Bt   = z == 0 ? WqT : (z == 1 ? WkT : WvT);
  const float*  bias = z == 0 ? bq  : (z == 1 ? bk  : bv);
  f32x4 acc[4][4] = {};
  const int mbase = blockIdx.y * 128, nbase = blockIdx.x * 128;
  gemm_core(A, Bt, As, Bs, mbase, nbase, acc);
  const int tid = threadIdx.x, lane = tid & 63, wave = tid >> 6;
  const int lrow = lane & 15, lg = lane >> 4, wm = wave >> 1, wn = wave & 1;
  if (z < 2) {
    bf16_t* Out = z == 0 ? Qp : Kp;
#pragma unroll
    for (int mt = 0; mt < 4; mt++) {
      int r0 = mbase + wm * 64 + mt * 16 + lg * 4;
#pragma unroll
      for (int nt = 0; nt < 4; nt++) {
        int col = nbase + wn * 64 + nt * 16 + lrow;
        float bb = bias[col];
#pragma unroll
        for (int r = 0; r < 4; r++)
          Out[(size_t)(r0 + r) * D_MOD + col] = (bf16_t)(acc[mt][nt][r] + bb);
      }
    }
  } else {
#pragma unroll
    for (int mt = 0; mt < 4; mt++) {
      int r0 = mbase + wm * 64 + mt * 16 + lg * 4;
      int b = r0 >> 11, s0 = r0 & (S_LEN - 1);  // 4 consecutive s, same b
#pragma unroll
      for (int nt = 0; nt < 4; nt++) {
        int col = nbase + wn * 64 + nt * 16 + lrow;  // h*64+hd
        float bb = bias[col];
        bf16x4 pk;
#pragma unroll
        for (int r = 0; r < 4; r++) pk[r] = (bf16_t)(acc[mt][nt][r] + bb);
        *(bf16x4*)(Vt + ((size_t)(b * NHEAD + (col >> 6)) * 64 + (col & 63)) * S_LEN + s0) = pk;
      }
    }
  }
}

// ---------------- flash attention v3 (proven 85 us): swapped QK^T, LDS-staged K/V ----------------
__global__ __launch_bounds__(256) void attn_kernel(
    const bf16_t* __restrict__ Q, const bf16_t* __restrict__ K,
    const bf16_t* __restrict__ Vt, bf16_t* __restrict__ O)
{
  __shared__ __align__(16) bf16_t Ks[2][64 * 64];
  __shared__ __align__(16) bf16_t Vs[2][64 * 64];
  __shared__ __align__(16) bf16_t plds[4][32 * 72];  // per-wave P relay, padded rows
  const int tid = threadIdx.x, wave = tid >> 6, lane = tid & 63;
  const int lrow = lane & 15, lg = lane >> 4;
  const int bh = blockIdx.y;             // 0..31
  const int b = bh >> 4, h = bh & 15;
  const int qbase = blockIdx.x * 128 + wave * 32;
  const bf16_t* Kb = K + (size_t)(b * S_LEN) * D_MOD + h * 64;
  const bf16_t* Vb = Vt + (size_t)bh * 64 * S_LEN;

  bf16x8 qf[2][2];
#pragma unroll
  for (int qr = 0; qr < 2; qr++) {
    const bf16_t* Qrow = Q + (size_t)(b * S_LEN + qbase + qr * 16 + lrow) * D_MOD + h * 64;
    qf[qr][0] = *(const bf16x8*)(Qrow + lg * 8);
    qf[qr][1] = *(const bf16x8*)(Qrow + 32 + lg * 8);
  }

  float mrow[2] = {-1e30f, -1e30f};
  float lsum[2] = {0.f, 0.f};
  f32x4 oacc[2][4] = {};

  bf16_t* pl = (bf16_t*)plds[wave];
  const float sc2 = 0.03125f * 1.44269504f;  // (1/sqrt(D)) * log2(e)
  const int rs = lrow & 7;

  auto stage = [&](int buf, int kt) {
#pragma unroll
    for (int j = 0; j < 2; j++) {
      int flat = j * 256 + tid;                 // 0..511
      int r = flat >> 3, c8 = flat & 7;
      int sc8 = c8 ^ (r & 7);
      gload_lds16(Kb + (size_t)(kt + r) * D_MOD + sc8 * 8, &Ks[buf][flat * 8]);
    }
#pragma unroll
    for (int j = 0; j < 2; j++) {
      int flat = j * 256 + tid;
      int r = flat >> 3, c8 = flat & 7;
      int sc8 = c8 ^ (r & 7);
      gload_lds16(Vb + (size_t)r * S_LEN + kt + sc8 * 8, &Vs[buf][flat * 8]);
    }
  };

  stage(0, 0);
  __syncthreads();

  for (int kt = 0; kt < S_LEN; kt += 64) {
    const int cur = (kt >> 6) & 1;
    if (kt + 64 < S_LEN) stage(cur ^ 1, kt + 64);
    const bf16_t* Kc = Ks[cur];
    const bf16_t* Vc = Vs[cur];

    bf16x8 kf[4][2];
#pragma unroll
    for (int ct = 0; ct < 4; ct++) {
      int row = ct * 16 + lrow;
      kf[ct][0] = *(const bf16x8*)(Kc + row * 64 + ((lg) ^ rs) * 8);
      kf[ct][1] = *(const bf16x8*)(Kc + row * 64 + ((4 + lg) ^ rs) * 8);
    }
    f32x4 st[2][4] = {};
    __builtin_amdgcn_s_setprio(1);
#pragma unroll
    for (int qr = 0; qr < 2; qr++)
#pragma unroll
      for (int ct = 0; ct < 4; ct++) {
        st[qr][ct] = mfma16(kf[ct][0], qf[qr][0], st[qr][ct]);
        st[qr][ct] = mfma16(kf[ct][1], qf[qr][1], st[qr][ct]);
      }
    __builtin_amdgcn_s_setprio(0);

    float corr_pv[2][4];
#pragma unroll
    for (int qr = 0; qr < 2; qr++) {
      f32x4 m01, m23, mm;
#pragma unroll
      for (int r = 0; r < 4; r++) {
        m01[r] = fmaxf(st[qr][0][r], st[qr][1][r]);
        m23[r] = fmaxf(st[qr][2][r], st[qr][3][r]);
        mm[r] = fmaxf(m01[r], m23[r]);
      }
      float rmax = fmaxf(fmaxf(mm[0], mm[1]), fmaxf(mm[2], mm[3]));
      rmax = fmaxf(rmax, __shfl_xor(rmax, 16));
      rmax = fmaxf(rmax, __shfl_xor(rmax, 32));
      float mn = fmaxf(mrow[qr], rmax * sc2);
      float corr = __builtin_amdgcn_exp2f(mrow[qr] - mn);
      mrow[qr] = mn;
      f32x4 p[4];
      f32x4 ps;
#pragma unroll
      for (int r = 0; r < 4; r++) {
        p[0][r] = __builtin_amdgcn_exp2f(__builtin_fmaf(st[qr][0][r], sc2, -mn));
        p[1][r] = __builtin_amdgcn_exp2f(__builtin_fmaf(st[qr][1][r], sc2, -mn));
        p[2][r] = __builtin_amdgcn_exp2f(__builtin_fmaf(st[qr][2][r], sc2, -mn));
        p[3][r] = __builtin_amdgcn_exp2f(__builtin_fmaf(st[qr][3][r], sc2, -mn));
        ps[r] = (p[0][r] + p[1][r]) + (p[2][r] + p[3][r]);
      }
      float rsum = (ps[0] + ps[1]) + (ps[2] + ps[3]);
      rsum += __shfl_xor(rsum, 16);
      rsum += __shfl_xor(rsum, 32);
      lsum[qr] = lsum[qr] * corr + rsum;
#pragma unroll
      for (int ct = 0; ct < 4; ct++) {
        bf16x4 pk;
#pragma unroll
        for (int r = 0; r < 4; r++) pk[r] = (bf16_t)p[ct][r];
        *(bf16x4*)(pl + (qr * 16 + lrow) * 72 + ct * 16 + lg * 4) = pk;
      }
#pragma unroll
      for (int r = 0; r < 4; r++)
        corr_pv[qr][r] = __shfl(corr, lg * 4 + r);
    }
#pragma unroll
    for (int qr = 0; qr < 2; qr++)
#pragma unroll
      for (int nt = 0; nt < 4; nt++)
#pragma unroll
        for (int r = 0; r < 4; r++)
          oacc[qr][nt][r] *= corr_pv[qr][r];

    bf16x8 vf[4][2];
#pragma unroll
    for (int nt = 0; nt < 4; nt++) {
      int row = nt * 16 + lrow;
      vf[nt][0] = *(const bf16x8*)(Vc + row * 64 + ((lg) ^ rs) * 8);
      vf[nt][1] = *(const bf16x8*)(Vc + row * 64 + ((4 + lg) ^ rs) * 8);
    }
    __builtin_amdgcn_s_setprio(1);
#pragma unroll
    for (int qr = 0; qr < 2; qr++)
#pragma unroll
      for (int kc = 0; kc < 2; kc++) {
        bf16x8 af = *(const bf16x8*)(pl + (qr * 16 + lrow) * 72 + kc * 32 + lg * 8);
#pragma unroll
        for (int nt = 0; nt < 4; nt++)
          oacc[qr][nt] = mfma16(af, vf[nt][kc], oacc[qr][nt]);
      }
    __builtin_amdgcn_s_setprio(0);

    __syncthreads();
  }

  bf16_t* Or = O + (size_t)(b * S_LEN + qbase) * D_MOD + h * 64;
#pragma unroll
  for (int qr = 0; qr < 2; qr++) {
    float linv[4];
#pragma unroll
    for (int r = 0; r < 4; r++)
      linv[r] = 1.f / __shfl(lsum[qr], lg * 4 + r);
#pragma unroll
    for (int r = 0; r < 4; r++)
#pragma unroll
      for (int nt = 0; nt < 4; nt++)
        Or[(size_t)(qr * 16 + lg * 4 + r) * D_MOD + nt * 16 + lrow] = (bf16_t)(oacc[qr][nt][r] * linv[r]);
  }
}

// ---------------- output projection: fp32 out ----------------
__global__ __launch_bounds__(256) void gemm_o_kernel(
    const bf16_t* __restrict__ A, const bf16_t* __restrict__ Bt,
    const float* __restrict__ bias, float* __restrict__ Out)
{
  __shared__ __align__(16) bf16_t As[2 * 128 * 64];
  __shared__ __align__(16) bf16_t Bs[2 * 128 * 64];
  f32x4 acc[4][4] = {};
  const int mbase = blockIdx.y * 128, nbase = blockIdx.x * 128;
  gemm_core(A, Bt, As, Bs, mbase, nbase, acc);
  const int tid = threadIdx.x, lane = tid & 63, wave = tid >> 6;
  const int lrow = lane & 15, lg = lane >> 4, wm = wave >> 1, wn = wave & 1;
#pragma unroll
  for (int mt = 0; mt < 4; mt++) {
    int r0 = mbase + wm * 64 + mt * 16 + lg * 4;
#pragma unroll
    for (int nt = 0; nt < 4; nt++) {
      int col = nbase + wn * 64 + nt * 16 + lrow;
      float bb = bias[col];
#pragma unroll
      for (int r = 0; r < 4; r++)
        Out[(size_t)(r0 + r) * D_MOD + col] = acc[mt][nt][r] + bb;
    }
  }
}

extern "C" void kernel_launch(void* const* d_in, const int* in_sizes, int n_in,
                              void* d_out, int out_size, void* d_ws, size_t ws_size,
                              hipStream_t stream) {
  const float* q  = (const float*)d_in[0];
  const float* k  = (const float*)d_in[1];
  const float* v  = (const float*)d_in[2];
  const float* Wq = (const float*)d_in[3];
  const float* bq = (const float*)d_in[4];
  const float* Wk = (const float*)d_in[5];
  const float* bk = (const float*)d_in[6];
  const float* Wv = (const float*)d_in[7];
  const float* bv = (const float*)d_in[8];
  const float* Wo = (const float*)d_in[9];
  const float* bo = (const float*)d_in[10];
  float* out = (float*)d_out;

  char* ws = (char*)d_ws;
  const size_t MB = 1024 * 1024;
  bf16_t* Xq  = (bf16_t*)(ws + 0 * MB);   // 8 MB each
  bf16_t* Xk  = (bf16_t*)(ws + 8 * MB);
  bf16_t* Xv  = (bf16_t*)(ws + 16 * MB);
  bf16_t* WqT = (bf16_t*)(ws + 24 * MB);  // 2 MB each
  bf16_t* WkT = (bf16_t*)(ws + 26 * MB);
  bf16_t* WvT = (bf16_t*)(ws + 28 * MB);
  bf16_t* WoT = (bf16_t*)(ws + 30 * MB);
  bf16_t* Qp  = (bf16_t*)(ws + 32 * MB);
  bf16_t* Kp  = (bf16_t*)(ws + 40 * MB);
  bf16_t* Vt  = (bf16_t*)(ws + 48 * MB);
  bf16_t* AO  = (bf16_t*)(ws + 0 * MB);   // reuse Xq (consumed before attn)

  dim3 cb(256);
  cvt3_kernel<<<dim3(4096, 1, 3), cb, 0, stream>>>(q, k, v, Xq, Xk, Xv);
  wtrans_kernel<<<dim3(16, 16, 4), cb, 0, stream>>>(Wq, Wk, Wv, Wo, WqT, WkT, WvT, WoT);
  gemm_qkv_kernel<<<dim3(8, 32, 3), cb, 0, stream>>>(Xq, Xk, Xv, WqT, WkT, WvT,
                                                     bq, bk, bv, Qp, Kp, Vt);
  attn_kernel<<<dim3(16, 32), cb, 0, stream>>>(Qp, Kp, Vt, AO);
  gemm_o_kernel<<<dim3(8, 32), cb, 0, stream>>>(AO, WoT, bo, out);
}